// Round 20
// baseline (181.785 us; speedup 1.0000x reference)
//
#include <hip/hip_runtime.h>

#define NU 8192
#define NI 8192
#define DD 128

typedef float fx4 __attribute__((ext_vector_type(4)));
typedef int   ix4 __attribute__((ext_vector_type(4)));
typedef short bx8 __attribute__((ext_vector_type(8)));
typedef short sx4 __attribute__((ext_vector_type(4)));

__device__ __forceinline__ short f2bf(float f) {
  unsigned u = __float_as_uint(f);
  u = (u + 0x7FFFu + ((u >> 16) & 1u)) >> 16;   // RNE f32 -> bf16
  return (short)u;
}
__device__ __forceinline__ float lrelu(float x) { return fmaxf(x, 0.2f * x); }

// ---- K1: prep — W->LDS; v1/v2; WiT tile (16 rows); a1 (16 rows); e1/e2 + blkmax.
// 512 blocks x 256 thr (2 blocks/CU). Block b owns i-rows and u-rows b*16..b*16+15.
__global__ __launch_bounds__(256) void k_prep(
    const float* __restrict__ hU, const float* __restrict__ hI,
    const float* __restrict__ W, const float* __restrict__ a,
    float* __restrict__ a1, float* __restrict__ e1, float* __restrict__ e2,
    short* __restrict__ WiT, float* __restrict__ blkmax)
{
  __shared__ float Wl[128 * 128];
  __shared__ float vv[2][128];
  __shared__ float red[16];
  const int tid = threadIdx.x;
#pragma unroll
  for (int it = 0; it < 16; ++it) {
    int idx = it * 1024 + tid * 4;
    *(fx4*)(Wl + idx) = *(const fx4*)(W + idx);
  }
  __syncthreads();
  if (tid < 128) {
    float s1 = 0.f, s2 = 0.f;
    for (int k = 0; k < DD; ++k) {
      float w = Wl[k * 128 + tid];
      s1 += a[k] * w;
      s2 += a[DD + k] * w;
    }
    vv[0][tid] = s1; vv[1][tid] = s2;
  }
  __syncthreads();

  const int i0 = blockIdx.x * 16;

  // WiT tile (rows i0..i0+15): thread = (row rg, 8-col group kg)
  {
    const int rg = tid & 15;
    const int kg = tid >> 4;          // 0..15
    const int r0 = i0 + rg;
    const int k0 = kg * 8;
    float acc[8];
#pragma unroll
    for (int c = 0; c < 8; ++c) acc[c] = 0.f;
    for (int j = 0; j < 128; j += 4) {
      fx4 wv8[8];
#pragma unroll
      for (int c = 0; c < 8; ++c) wv8[c] = *(const fx4*)(Wl + (k0 + c) * 128 + j);
      const fx4 hv = *(const fx4*)(hI + (size_t)r0 * DD + j);
#pragma unroll
      for (int c = 0; c < 8; ++c)
        acc[c] += hv[0]*wv8[c][0] + hv[1]*wv8[c][1] + hv[2]*wv8[c][2] + hv[3]*wv8[c][3];
    }
#pragma unroll
    for (int c = 0; c < 8; ++c)
      WiT[(size_t)(k0 + c) * NI + r0] = f2bf(acc[c]);
  }

  // row dots: tid<16 -> a1 (u-rows); tid in [64,80) -> e-tables + max (i-rows)
  if (tid < 16) {
    const int row = i0 + tid;
    const fx4* hv = (const fx4*)(hU + (size_t)row * DD);
    const fx4* vq = (const fx4*)&vv[0][0];
    float s = 0.f;
#pragma unroll
    for (int q = 0; q < DD / 4; ++q) {
      fx4 hq = hv[q], vqq = vq[q];
      s += hq[0]*vqq[0] + hq[1]*vqq[1] + hq[2]*vqq[2] + hq[3]*vqq[3];
    }
    a1[row] = s;
  } else if (tid >= 64 && tid < 80) {
    const int row = i0 + (tid - 64);
    const fx4* hv = (const fx4*)(hI + (size_t)row * DD);
    const fx4* vq = (const fx4*)&vv[1][0];
    float s = 0.f;
#pragma unroll
    for (int q = 0; q < DD / 4; ++q) {
      fx4 hq = hv[q], vqq = vq[q];
      s += hq[0]*vqq[0] + hq[1]*vqq[1] + hq[2]*vqq[2] + hq[3]*vqq[3];
    }
    e1[row] = __expf(s);
    e2[row] = __expf(0.2f * s);
    red[tid - 64] = s;
  }
  __syncthreads();
  if (tid == 0) {
    float m = red[0];
#pragma unroll
    for (int k = 1; k < 16; ++k) m = fmaxf(m, red[k]);
    blkmax[blockIdx.x] = m;
  }
}

// ---- K3: fused adj-read + alpha-write + mask + kcons. 1 row/block, 512 thr.
// Prologue computes mA2 = max(blkmax[0..511]) in-block, hidden under adj loads.
__global__ __launch_bounds__(512, 4) void k_fuseA(
    const int* __restrict__ adj, const float* __restrict__ a1g,
    const float* __restrict__ e1g, const float* __restrict__ e2g,
    const float* __restrict__ blkmax,
    fx4* __restrict__ kcons, unsigned* __restrict__ mask,
    float* __restrict__ alphap)
{
  const int row  = blockIdx.x;
  const int tid  = threadIdx.x;
  const int lane = tid & 63;
  const int wv   = tid >> 6;       // 0..7
  const size_t base = (size_t)row * NI;
  ix4 m[4];
#pragma unroll
  for (int q = 0; q < 4; ++q)
    m[q] = __builtin_nontemporal_load((const ix4*)(adj + base + q * 2048 + tid * 4));

  // block-local max of the 512 per-prep-block maxes (hides under adj loads)
  __shared__ float smax[8];
  __shared__ float lp[8];
  {
    float bm = blkmax[tid];
#pragma unroll
    for (int st = 1; st < 64; st <<= 1) bm = fmaxf(bm, __shfl_xor(bm, st, 64));
    if (lane == 0) smax[wv] = bm;
  }
  __syncthreads();
  float mA2 = smax[0];
#pragma unroll
  for (int w = 1; w < 8; ++w) mA2 = fmaxf(mA2, smax[w]);

  const float A  = a1g[row];
  const float C  = lrelu(A + mA2);
  const float K1 = __expf(A - C);
  const float K2 = __expf(0.2f * A - C);
  const float T1 = __expf(-A);     // sel <=> E1[i] > T1 <=> a1+a2 > 0
  fx4 p[4];
  float ps = 0.f;
#pragma unroll
  for (int q = 0; q < 4; ++q) {
    const int i0 = q * 2048 + tid * 4;
    const fx4 E1 = *(const fx4*)(e1g + i0);
    const fx4 E2 = *(const fx4*)(e2g + i0);
    unsigned long long b[4];
#pragma unroll
    for (int e = 0; e < 4; ++e) {
      const bool mm  = (m[q][e] != 0);
      const bool sel = (E1[e] > T1);
      const float val = sel ? E1[e] * K1 : E2[e] * K2;
      const float pv  = mm ? val : 0.f;
      p[q][e] = pv;
      ps += pv;
      b[e] = __ballot(mm);
    }
    if (lane < 8) {
      unsigned w = 0u;
#pragma unroll
      for (int e = 0; e < 4; ++e) {
        unsigned x = (unsigned)((b[e] >> (lane * 8)) & 0xFFull);
        x = (x | (x << 12)) & 0x000F000Fu;    // spread 8 bits -> every 4th bit
        x = (x | (x << 6))  & 0x03030303u;
        x = (x | (x << 3))  & 0x11111111u;
        w |= x << e;
      }
      mask[(size_t)row * 256 + q * 64 + wv * 8 + lane] = w;
    }
  }
#pragma unroll
  for (int st = 1; st < 64; st <<= 1) ps += __shfl_xor(ps, st, 64);
  if (lane == 0) lp[wv] = ps;
  __syncthreads();
  const float l  = ((lp[0] + lp[1]) + (lp[2] + lp[3]))
                 + ((lp[4] + lp[5]) + (lp[6] + lp[7]));
  const float ri = (l > 0.f) ? (1.f / l) : 0.f;
#pragma unroll
  for (int q = 0; q < 4; ++q) {
    fx4 o;
#pragma unroll
    for (int e = 0; e < 4; ++e) o[e] = p[q][e] * ri;
    __builtin_nontemporal_store(o, (fx4*)(alphap + base + q * 2048 + tid * 4));
  }
  if (tid == 0) kcons[row] = (fx4){K1 * ri, K2 * ri, T1, ri};
}

// ---- K4: pure out-partial GEMM, LDS-staged B, register-blocked M.
// 8 waves = 2 wmg(32 rows) x 2 kk x 2 nn(64 cols). Each wave: 2 af (shared
// e-loads), 4 bf each feeding 2 MFMAs (bf:MFMA = 1:2 -> LDS reads halved).
// grid 512 = 128 uTiles(64 rows) x 4 K-quarters; 512 thr; (512,4).
__global__ __launch_bounds__(512, 4) void k_gemm(
    const unsigned* __restrict__ mask, const fx4* __restrict__ kcons,
    const float* __restrict__ e1g, const float* __restrict__ e2g,
    const short* __restrict__ WiT, float* __restrict__ partial)
{
  __shared__ __align__(16) char lds[32768];
  const int tid  = threadIdx.x;
  const int lane = tid & 63;
  const int wv   = tid >> 6;
  const int wmg  = wv & 1;         // 32-row group
  const int kk   = (wv >> 1) & 1;  // k-step within chunk
  const int nn   = wv >> 2;        // 64-col half
  const int uTile = (int)blockIdx.x >> 2;
  const int quar  = (int)blockIdx.x & 3;
  const int u0 = uTile * 64;
  const int ib = quar * 2048;
  const int lr = lane & 15, lg = lane >> 4;

  // two m-frag rows (16 apart) — pre-normalized constants
  const int row0 = u0 + wmg * 32 + lr;
  const int row1 = row0 + 16;
  const fx4 kc0 = kcons[row0];
  const fx4 kc1 = kcons[row1];
  const unsigned* mrow0 = mask + (size_t)row0 * 256 + quar * 64;
  const unsigned* mrow1 = mask + (size_t)row1 * 256 + quar * 64;

  // staging map: thread covers (d = tid>>3 and d+64, i8 = tid&7)
  const int sd = tid >> 3;
  const int si = tid & 7;
  const short* g0 = WiT + (size_t)sd * NI + ib + si * 8;
  const short* g1 = WiT + (size_t)(sd + 64) * NI + ib + si * 8;
  const int swz = (si * 16) ^ ((sd & 7) << 4);
  const int w0 = sd * 128 + swz;
  const int w1 = (sd + 64) * 128 + swz;

  fx4 acc[2][4];
#pragma unroll
  for (int mg = 0; mg < 2; ++mg)
#pragma unroll
    for (int n = 0; n < 4; ++n) acc[mg][n] = (fx4){0.f, 0.f, 0.f, 0.f};

  // prolog: stage chunk 0 into buf0
  bx8 sA = *(const bx8*)g0;
  bx8 sB = *(const bx8*)g1;
  *(bx8*)(lds + w0) = sA;
  *(bx8*)(lds + w1) = sB;

  for (int c = 0; c < 32; ++c) {
    char* buf = lds + (c & 1) * 16384;
    const int nxt = ((c + 1) & 1) * 16384;
    if (c < 31) {                       // issue next-chunk loads early
      sA = *(const bx8*)(g0 + (c + 1) * 64);
      sB = *(const bx8*)(g1 + (c + 1) * 64);
    }
    __syncthreads();                    // buf[c&1] ready; prior reads of nxt done

    // ---- MFMA phase: this wave's single k-step (ks = c*2 + kk) ----
    {
      const int ksg = c * 2 + kk;       // 0..63
      const int io = ksg * 32 + lg * 8;
      const fx4 e1a = *(const fx4*)(e1g + ib + io);
      const fx4 e1b = *(const fx4*)(e1g + ib + io + 4);
      const fx4 e2a = *(const fx4*)(e2g + ib + io);
      const fx4 e2b = *(const fx4*)(e2g + ib + io + 4);
      const unsigned by0 = (mrow0[ksg] >> (lg * 8)) & 0xFFu;
      const unsigned by1 = (mrow1[ksg] >> (lg * 8)) & 0xFFu;
      bx8 af0, af1;
#pragma unroll
      for (int j = 0; j < 8; ++j) {
        const float e1v = (j < 4) ? e1a[j] : e1b[j - 4];
        const float e2v = (j < 4) ? e2a[j] : e2b[j - 4];
        const float v0 = (e1v > kc0[2]) ? e1v * kc0[0] : e2v * kc0[1];
        const float v1 = (e1v > kc1[2]) ? e1v * kc1[0] : e2v * kc1[1];
        af0[j] = ((by0 >> j) & 1u) ? f2bf(v0) : (short)0;
        af1[j] = ((by1 >> j) & 1u) ? f2bf(v1) : (short)0;
      }
#pragma unroll
      for (int nf = 0; nf < 4; ++nf) {
        const int d = nn * 64 + nf * 16 + lr;
        const bx8 bf = *(const bx8*)(buf + d * 128 +
                        ((kk * 64 + lg * 16) ^ ((lr & 7) << 4)));
        acc[0][nf] = __builtin_amdgcn_mfma_f32_16x16x32_bf16(af0, bf, acc[0][nf], 0, 0, 0);
        acc[1][nf] = __builtin_amdgcn_mfma_f32_16x16x32_bf16(af1, bf, acc[1][nf], 0, 0, 0);
      }
    }

    if (c < 31) {                       // write next chunk (load hidden by MFMA)
      *(bx8*)(lds + nxt + w0) = sA;
      *(bx8*)(lds + nxt + w1) = sB;
    }
  }

  // epilogue: cross-kk reduce via LDS (reuse staging buffer), store partials
  __syncthreads();                      // all waves done reading lds
  float* red = (float*)lds;             // 64 rows x 128 cols f32 = 32 KB
  if (kk == 0) {
#pragma unroll
    for (int mg = 0; mg < 2; ++mg)
#pragma unroll
      for (int nf = 0; nf < 4; ++nf)
#pragma unroll
        for (int v = 0; v < 4; ++v)
          red[(wmg * 32 + mg * 16 + lg * 4 + v) * 128 + nn * 64 + nf * 16 + lr]
            = acc[mg][nf][v];
  }
  __syncthreads();
  if (kk == 1) {
    float* pb = partial + (size_t)blockIdx.x * (64 * 128);
#pragma unroll
    for (int mg = 0; mg < 2; ++mg)
#pragma unroll
      for (int nf = 0; nf < 4; ++nf)
#pragma unroll
        for (int v = 0; v < 4; ++v) {
          const int idx = (wmg * 32 + mg * 16 + lg * 4 + v) * 128
                        + nn * 64 + nf * 16 + lr;
          pb[idx] = red[idx] + acc[mg][nf][v];
        }
  }
}

// ---- K5: out[u][d] = sum of 4 K-quarter partials (already normalized)
__global__ __launch_bounds__(512) void k_comb(
    const float* __restrict__ partial, float* __restrict__ outp)
{
  const int g = blockIdx.x * 512 + threadIdx.x;   // 0..262143 (fx4 units)
  const int u = g >> 5;
  const int c4 = (g & 31) * 4;
  const int uTile = u >> 6, r = u & 63;
  const float* p0 = partial + ((size_t)uTile * 4) * 8192 + r * 128 + c4;
  fx4 s = *(const fx4*)p0;
#pragma unroll
  for (int q = 1; q < 4; ++q) {
    fx4 t = *(const fx4*)(p0 + (size_t)q * 8192);
    s[0] += t[0]; s[1] += t[1]; s[2] += t[2]; s[3] += t[3];
  }
  *(fx4*)(outp + (size_t)u * DD + c4) = s;
}

extern "C" void kernel_launch(void* const* d_in, const int* in_sizes, int n_in,
                              void* d_out, int out_size, void* d_ws, size_t ws_size,
                              hipStream_t stream) {
  (void)in_sizes; (void)n_in; (void)out_size; (void)ws_size;
  const float* h_u = (const float*)d_in[0];
  const float* h_i = (const float*)d_in[1];
  const int*   adj = (const int*)d_in[2];
  const float* W   = (const float*)d_in[3];
  const float* a   = (const float*)d_in[4];

  float* outp   = (float*)d_out;                       // [8192][128]
  float* alphap = (float*)d_out + (size_t)NU * DD;     // [8192][8192]

  char* ws = (char*)d_ws;
  float*    blkmax = (float*)(ws + 2048);     // 512 f32 (ends 4096)
  float*    a1     = (float*)(ws + 4096);     // 8192 f32
  float*    e1t    = (float*)(ws + 102400);   // 8192 f32: exp(a2)
  float*    e2t    = (float*)(ws + 135168);   // 8192 f32: exp(0.2 a2)
  short*    WiT    = (short*)(ws + 262144);   // 128*8192 bf16 = 2 MiB
  unsigned* mask   = (unsigned*)(ws + 2359296); // 8192*256 u32 = 8 MiB
  float*    part   = (float*)(ws + 11534336); // 512*64*128 f32 = 16 MiB
  fx4*      kcons  = (fx4*)(ws + 29360128);   // 8192 fx4 = 128 KiB

  k_prep  <<<512,  256, 0, stream>>>(h_u, h_i, W, a, a1, e1t, e2t, WiT, blkmax);
  k_fuseA <<<NU,   512, 0, stream>>>(adj, a1, e1t, e2t, blkmax, kcons, mask, alphap);
  k_gemm  <<<512,  512, 0, stream>>>(mask, kcons, e1t, e2t, WiT, part);
  k_comb  <<<512,  512, 0, stream>>>(part, outp);
}

// Round 21
// 166.132 us; speedup vs baseline: 1.0942x; 1.0942x over previous
//
#include <hip/hip_runtime.h>

#define NU 8192
#define NI 8192
#define DD 128

typedef float fx4 __attribute__((ext_vector_type(4)));
typedef int   ix4 __attribute__((ext_vector_type(4)));
typedef short bx8 __attribute__((ext_vector_type(8)));
typedef short sx4 __attribute__((ext_vector_type(4)));

__device__ __forceinline__ short f2bf(float f) {
  unsigned u = __float_as_uint(f);
  u = (u + 0x7FFFu + ((u >> 16) & 1u)) >> 16;   // RNE f32 -> bf16
  return (short)u;
}
__device__ __forceinline__ float lrelu(float x) { return fmaxf(x, 0.2f * x); }

// ---- K1: prep — W->LDS; v1/v2; WiT tile (16 rows); a1 (16 rows); e1/e2 + blkmax.
// 512 blocks x 256 thr (2 blocks/CU). Block b owns i-rows and u-rows b*16..b*16+15.
__global__ __launch_bounds__(256) void k_prep(
    const float* __restrict__ hU, const float* __restrict__ hI,
    const float* __restrict__ W, const float* __restrict__ a,
    float* __restrict__ a1, float* __restrict__ e1, float* __restrict__ e2,
    short* __restrict__ WiT, float* __restrict__ blkmax)
{
  __shared__ float Wl[128 * 128];
  __shared__ float vv[2][128];
  __shared__ float red[16];
  const int tid = threadIdx.x;
#pragma unroll
  for (int it = 0; it < 16; ++it) {
    int idx = it * 1024 + tid * 4;
    *(fx4*)(Wl + idx) = *(const fx4*)(W + idx);
  }
  __syncthreads();
  if (tid < 128) {
    float s1 = 0.f, s2 = 0.f;
    for (int k = 0; k < DD; ++k) {
      float w = Wl[k * 128 + tid];
      s1 += a[k] * w;
      s2 += a[DD + k] * w;
    }
    vv[0][tid] = s1; vv[1][tid] = s2;
  }
  __syncthreads();

  const int i0 = blockIdx.x * 16;

  // WiT tile (rows i0..i0+15): thread = (row rg, 8-col group kg)
  {
    const int rg = tid & 15;
    const int kg = tid >> 4;          // 0..15
    const int r0 = i0 + rg;
    const int k0 = kg * 8;
    float acc[8];
#pragma unroll
    for (int c = 0; c < 8; ++c) acc[c] = 0.f;
    for (int j = 0; j < 128; j += 4) {
      fx4 wv8[8];
#pragma unroll
      for (int c = 0; c < 8; ++c) wv8[c] = *(const fx4*)(Wl + (k0 + c) * 128 + j);
      const fx4 hv = *(const fx4*)(hI + (size_t)r0 * DD + j);
#pragma unroll
      for (int c = 0; c < 8; ++c)
        acc[c] += hv[0]*wv8[c][0] + hv[1]*wv8[c][1] + hv[2]*wv8[c][2] + hv[3]*wv8[c][3];
    }
#pragma unroll
    for (int c = 0; c < 8; ++c)
      WiT[(size_t)(k0 + c) * NI + r0] = f2bf(acc[c]);
  }

  // row dots: tid<16 -> a1 (u-rows); tid in [64,80) -> e-tables + max (i-rows)
  if (tid < 16) {
    const int row = i0 + tid;
    const fx4* hv = (const fx4*)(hU + (size_t)row * DD);
    const fx4* vq = (const fx4*)&vv[0][0];
    float s = 0.f;
#pragma unroll
    for (int q = 0; q < DD / 4; ++q) {
      fx4 hq = hv[q], vqq = vq[q];
      s += hq[0]*vqq[0] + hq[1]*vqq[1] + hq[2]*vqq[2] + hq[3]*vqq[3];
    }
    a1[row] = s;
  } else if (tid >= 64 && tid < 80) {
    const int row = i0 + (tid - 64);
    const fx4* hv = (const fx4*)(hI + (size_t)row * DD);
    const fx4* vq = (const fx4*)&vv[1][0];
    float s = 0.f;
#pragma unroll
    for (int q = 0; q < DD / 4; ++q) {
      fx4 hq = hv[q], vqq = vq[q];
      s += hq[0]*vqq[0] + hq[1]*vqq[1] + hq[2]*vqq[2] + hq[3]*vqq[3];
    }
    e1[row] = __expf(s);
    e2[row] = __expf(0.2f * s);
    red[tid - 64] = s;
  }
  __syncthreads();
  if (tid == 0) {
    float m = red[0];
#pragma unroll
    for (int k = 1; k < 16; ++k) m = fmaxf(m, red[k]);
    blkmax[blockIdx.x] = m;
  }
}

// ---- K3: fused adj-read + alpha-write + mask + kcons. 1 row/block, 512 thr.
// Prologue computes mA2 = max(blkmax[0..511]) in-block, hidden under adj loads.
__global__ __launch_bounds__(512, 4) void k_fuseA(
    const int* __restrict__ adj, const float* __restrict__ a1g,
    const float* __restrict__ e1g, const float* __restrict__ e2g,
    const float* __restrict__ blkmax,
    fx4* __restrict__ kcons, unsigned* __restrict__ mask,
    float* __restrict__ alphap)
{
  const int row  = blockIdx.x;
  const int tid  = threadIdx.x;
  const int lane = tid & 63;
  const int wv   = tid >> 6;       // 0..7
  const size_t base = (size_t)row * NI;
  ix4 m[4];
#pragma unroll
  for (int q = 0; q < 4; ++q)
    m[q] = __builtin_nontemporal_load((const ix4*)(adj + base + q * 2048 + tid * 4));

  // block-local max of the 512 per-prep-block maxes (hides under adj loads)
  __shared__ float smax[8];
  __shared__ float lp[8];
  {
    float bm = blkmax[tid];
#pragma unroll
    for (int st = 1; st < 64; st <<= 1) bm = fmaxf(bm, __shfl_xor(bm, st, 64));
    if (lane == 0) smax[wv] = bm;
  }
  __syncthreads();
  float mA2 = smax[0];
#pragma unroll
  for (int w = 1; w < 8; ++w) mA2 = fmaxf(mA2, smax[w]);

  const float A  = a1g[row];
  const float C  = lrelu(A + mA2);
  const float K1 = __expf(A - C);
  const float K2 = __expf(0.2f * A - C);
  const float T1 = __expf(-A);     // sel <=> E1[i] > T1 <=> a1+a2 > 0
  fx4 p[4];
  float ps = 0.f;
#pragma unroll
  for (int q = 0; q < 4; ++q) {
    const int i0 = q * 2048 + tid * 4;
    const fx4 E1 = *(const fx4*)(e1g + i0);
    const fx4 E2 = *(const fx4*)(e2g + i0);
    unsigned long long b[4];
#pragma unroll
    for (int e = 0; e < 4; ++e) {
      const bool mm  = (m[q][e] != 0);
      const bool sel = (E1[e] > T1);
      const float val = sel ? E1[e] * K1 : E2[e] * K2;
      const float pv  = mm ? val : 0.f;
      p[q][e] = pv;
      ps += pv;
      b[e] = __ballot(mm);
    }
    if (lane < 8) {
      unsigned w = 0u;
#pragma unroll
      for (int e = 0; e < 4; ++e) {
        unsigned x = (unsigned)((b[e] >> (lane * 8)) & 0xFFull);
        x = (x | (x << 12)) & 0x000F000Fu;    // spread 8 bits -> every 4th bit
        x = (x | (x << 6))  & 0x03030303u;
        x = (x | (x << 3))  & 0x11111111u;
        w |= x << e;
      }
      mask[(size_t)row * 256 + q * 64 + wv * 8 + lane] = w;
    }
  }
#pragma unroll
  for (int st = 1; st < 64; st <<= 1) ps += __shfl_xor(ps, st, 64);
  if (lane == 0) lp[wv] = ps;
  __syncthreads();
  const float l  = ((lp[0] + lp[1]) + (lp[2] + lp[3]))
                 + ((lp[4] + lp[5]) + (lp[6] + lp[7]));
  const float ri = (l > 0.f) ? (1.f / l) : 0.f;
#pragma unroll
  for (int q = 0; q < 4; ++q) {
    fx4 o;
#pragma unroll
    for (int e = 0; e < 4; ++e) o[e] = p[q][e] * ri;
    __builtin_nontemporal_store(o, (fx4*)(alphap + base + q * 2048 + tid * 4));
  }
  if (tid == 0) kcons[row] = (fx4){K1 * ri, K2 * ri, T1, ri};
}

// ---- K4: pure out-partial GEMM, LDS-staged B. Waves split over k (4 wm x 2 kk).
// grid 512 = 128 uTiles(64 rows) x 4 K-quarters; 512 thr; (512,4). [r15/r19 best]
__global__ __launch_bounds__(512, 4) void k_gemm(
    const unsigned* __restrict__ mask, const fx4* __restrict__ kcons,
    const float* __restrict__ e1g, const float* __restrict__ e2g,
    const short* __restrict__ WiT, float* __restrict__ partial)
{
  __shared__ __align__(16) char lds[32768];
  const int tid  = threadIdx.x;
  const int lane = tid & 63;
  const int wv   = tid >> 6;
  const int wm   = wv & 3;         // m-frag (16 rows each)
  const int kk   = wv >> 2;        // 0..1: k-step within chunk
  const int uTile = (int)blockIdx.x >> 2;
  const int quar  = (int)blockIdx.x & 3;
  const int u0 = uTile * 64;
  const int ib = quar * 2048;
  const int lr = lane & 15, lg = lane >> 4;

  // MFMA-row constants (row = u0 + wm*16 + lr) — pre-normalized
  const int rowm = u0 + wm * 16 + lr;
  const fx4 kcm = kcons[rowm];
  const float K1m = kcm[0], K2m = kcm[1], T1m = kcm[2];
  const unsigned* mrow = mask + (size_t)rowm * 256 + quar * 64;

  // staging map: thread covers (d = tid>>3 and d+64, i8 = tid&7)
  const int sd = tid >> 3;
  const int si = tid & 7;
  const short* g0 = WiT + (size_t)sd * NI + ib + si * 8;
  const short* g1 = WiT + (size_t)(sd + 64) * NI + ib + si * 8;
  const int swz = (si * 16) ^ ((sd & 7) << 4);
  const int w0 = sd * 128 + swz;
  const int w1 = (sd + 64) * 128 + swz;

  fx4 acc[8];
#pragma unroll
  for (int n = 0; n < 8; ++n) acc[n] = (fx4){0.f, 0.f, 0.f, 0.f};

  // prolog: stage chunk 0 into buf0
  bx8 sA = *(const bx8*)g0;
  bx8 sB = *(const bx8*)g1;
  *(bx8*)(lds + w0) = sA;
  *(bx8*)(lds + w1) = sB;

  for (int c = 0; c < 32; ++c) {
    char* buf = lds + (c & 1) * 16384;
    const int nxt = ((c + 1) & 1) * 16384;
    if (c < 31) {                       // issue next-chunk loads early
      sA = *(const bx8*)(g0 + (c + 1) * 64);
      sB = *(const bx8*)(g1 + (c + 1) * 64);
    }
    __syncthreads();                    // buf[c&1] ready; prior reads of nxt done

    // ---- MFMA phase: this wave's single k-step (ks = c*2 + kk) ----
    {
      const int ksg = c * 2 + kk;       // 0..63
      const unsigned by = (mrow[ksg] >> (lg * 8)) & 0xFFu;
      const int io = ksg * 32 + lg * 8;
      const fx4 e1a = *(const fx4*)(e1g + ib + io);
      const fx4 e1b = *(const fx4*)(e1g + ib + io + 4);
      const fx4 e2a = *(const fx4*)(e2g + ib + io);
      const fx4 e2b = *(const fx4*)(e2g + ib + io + 4);
      bx8 af;
#pragma unroll
      for (int j = 0; j < 8; ++j) {
        const float e1v = (j < 4) ? e1a[j] : e1b[j - 4];
        const float e2v = (j < 4) ? e2a[j] : e2b[j - 4];
        const float val = (e1v > T1m) ? e1v * K1m : e2v * K2m;
        af[j] = ((by >> j) & 1u) ? f2bf(val) : (short)0;
      }
#pragma unroll
      for (int nf = 0; nf < 8; ++nf) {
        const int d = nf * 16 + lr;
        const bx8 bf = *(const bx8*)(buf + d * 128 +
                        ((kk * 64 + lg * 16) ^ ((lr & 7) << 4)));
        acc[nf] = __builtin_amdgcn_mfma_f32_16x16x32_bf16(af, bf, acc[nf], 0, 0, 0);
      }
    }

    if (c < 31) {                       // write next chunk (load hidden by MFMA)
      *(bx8*)(lds + nxt + w0) = sA;
      *(bx8*)(lds + nxt + w1) = sB;
    }
  }

  // epilogue: cross-kk reduce via LDS (reuse staging buffer), store partials
  __syncthreads();                      // all waves done reading lds
  float* red = (float*)lds;             // 64 rows x 128 cols f32 = 32 KB
  if (kk == 0) {
#pragma unroll
    for (int nf = 0; nf < 8; ++nf)
#pragma unroll
      for (int v = 0; v < 4; ++v)
        red[(wm * 16 + lg * 4 + v) * 128 + nf * 16 + lr] = acc[nf][v];
  }
  __syncthreads();
  if (kk == 1) {
    float* pb = partial + (size_t)blockIdx.x * (64 * 128);
#pragma unroll
    for (int nf = 0; nf < 8; ++nf)
#pragma unroll
      for (int v = 0; v < 4; ++v) {
        const int idx = (wm * 16 + lg * 4 + v) * 128 + nf * 16 + lr;
        pb[idx] = red[idx] + acc[nf][v];
      }
  }
}

// ---- K5: out[u][d] = sum of 4 K-quarter partials (already normalized)
__global__ __launch_bounds__(512) void k_comb(
    const float* __restrict__ partial, float* __restrict__ outp)
{
  const int g = blockIdx.x * 512 + threadIdx.x;   // 0..262143 (fx4 units)
  const int u = g >> 5;
  const int c4 = (g & 31) * 4;
  const int uTile = u >> 6, r = u & 63;
  const float* p0 = partial + ((size_t)uTile * 4) * 8192 + r * 128 + c4;
  fx4 s = *(const fx4*)p0;
#pragma unroll
  for (int q = 1; q < 4; ++q) {
    fx4 t = *(const fx4*)(p0 + (size_t)q * 8192);
    s[0] += t[0]; s[1] += t[1]; s[2] += t[2]; s[3] += t[3];
  }
  *(fx4*)(outp + (size_t)u * DD + c4) = s;
}

extern "C" void kernel_launch(void* const* d_in, const int* in_sizes, int n_in,
                              void* d_out, int out_size, void* d_ws, size_t ws_size,
                              hipStream_t stream) {
  (void)in_sizes; (void)n_in; (void)out_size; (void)ws_size;
  const float* h_u = (const float*)d_in[0];
  const float* h_i = (const float*)d_in[1];
  const int*   adj = (const int*)d_in[2];
  const float* W   = (const float*)d_in[3];
  const float* a   = (const float*)d_in[4];

  float* outp   = (float*)d_out;                       // [8192][128]
  float* alphap = (float*)d_out + (size_t)NU * DD;     // [8192][8192]

  char* ws = (char*)d_ws;
  float*    blkmax = (float*)(ws + 2048);     // 512 f32 (ends 4096)
  float*    a1     = (float*)(ws + 4096);     // 8192 f32
  float*    e1t    = (float*)(ws + 102400);   // 8192 f32: exp(a2)
  float*    e2t    = (float*)(ws + 135168);   // 8192 f32: exp(0.2 a2)
  short*    WiT    = (short*)(ws + 262144);   // 128*8192 bf16 = 2 MiB
  unsigned* mask   = (unsigned*)(ws + 2359296); // 8192*256 u32 = 8 MiB
  float*    part   = (float*)(ws + 11534336); // 512*64*128 f32 = 16 MiB
  fx4*      kcons  = (fx4*)(ws + 29360128);   // 8192 fx4 = 128 KiB

  k_prep  <<<512,  256, 0, stream>>>(h_u, h_i, W, a, a1, e1t, e2t, WiT, blkmax);
  k_fuseA <<<NU,   512, 0, stream>>>(adj, a1, e1t, e2t, blkmax, kcons, mask, alphap);
  k_gemm  <<<512,  512, 0, stream>>>(mask, kcons, e1t, e2t, WiT, part);
  k_comb  <<<512,  512, 0, stream>>>(part, outp);
}